// Round 10
// baseline (231.092 us; speedup 1.0000x reference)
//
#include <hip/hip_runtime.h>
#include <hip/hip_bf16.h>

#define CH   192
#define PIX  4096   // 64*64 per image
#define BSZ  8

using f32x4  = __attribute__((ext_vector_type(4))) float;
using short8 = __attribute__((ext_vector_type(8))) short;

__device__ __forceinline__ float bf2f(unsigned short u) {
    union { unsigned u32; float f; } x; x.u32 = ((unsigned)u) << 16; return x.f;
}
__device__ __forceinline__ unsigned short f2bf(float f) {
    union { float f; unsigned u; } x; x.f = f;
    unsigned u = x.u;
    unsigned r = (u + 0x7FFFu + ((u >> 16) & 1u)) >> 16;  // RNE
    return (unsigned short)r;
}

// ---- prep: weights -> bf16 fragment-ordered; + tc; + gate-w transpose ---
__global__ void k_prep_w(const float* __restrict__ w0, const float* __restrict__ w1,
                         const float* __restrict__ ws0, const float* __restrict__ wo,
                         const float* __restrict__ ws1, const float* __restrict__ lc,
                         const float* __restrict__ wc0, const float* __restrict__ wc1,
                         unsigned short* __restrict__ w0f, unsigned short* __restrict__ w1f,
                         unsigned short* __restrict__ ws0xf, unsigned short* __restrict__ wof,
                         unsigned short* __restrict__ wc3f, float* __restrict__ tc,
                         float* __restrict__ wc0t, float* __restrict__ wc1t) {
    int i = blockIdx.x * 256 + threadIdx.x;
    if (i < 4*36864) {
        int which = i / 36864, j = i % 36864;
        int kc = j / 6144, r = j % 6144, mf = r / 512, r2 = r % 512;
        int l = r2 >> 3, e = r2 & 7;
        int o = mf*16 + (l & 15), k = kc*32 + ((l >> 4) << 3) + e;
        float v;
        unsigned short* dst;
        if (which == 0)      { v = w0[o*192 + k];  dst = w0f;   }
        else if (which == 1) { v = w1[o*192 + k];  dst = w1f;   }
        else if (which == 2) { v = ws0[o*384 + k]; dst = ws0xf; }
        else                 { v = wo[o*192 + k];  dst = wof;   }
        dst[j] = f2bf(v);
        return;
    }
    i -= 4*36864;
    if (i < 331776) {
        int tk = i / 6144, tap = tk / 6, kc = tk % 6;
        int r = i % 6144, mf = r / 512, r2 = r % 512;
        int l = r2 >> 3, e = r2 & 7;
        int o = mf*16 + (l & 15), c = kc*32 + ((l >> 4) << 3) + e;
        wc3f[i] = f2bf(ws1[(o*192 + c)*9 + tap]);
        return;
    }
    i -= 331776;
    if (i < 24576) {
        int bm = i / 192, o = i % 192;
        const float* wr = ws0 + o*384 + 192;
        const float* cb = lc + bm*192;
        float a = 0.f;
        for (int c2 = 0; c2 < 192; ++c2) a += wr[c2] * cb[c2];
        tc[i] = a;
        return;
    }
    i -= 24576;
    if (i < 36864) { int o = i / 192, c = i % 192; wc0t[c*192 + o] = wc0[o*192 + c]; return; }
    i -= 36864;
    if (i < 36864) { int o = i / 192, c = i % 192; wc1t[c*192 + o] = wc1[o*192 + c]; }
}

// ---- fused triple 1x1 GEMM: input(fp32) -> h -> x -> y0T + in_bf --------
__global__ __launch_bounds__(256) void k_fused3(
    const float* __restrict__ input,
    const unsigned short* __restrict__ w0f,
    const unsigned short* __restrict__ w1f,
    const unsigned short* __restrict__ ws0xf,
    const float* __restrict__ b0, const float* __restrict__ b1,
    const float* __restrict__ bs0,
    const float* __restrict__ tc, const int* __restrict__ mask,
    unsigned short* __restrict__ xg, unsigned short* __restrict__ y0t,
    unsigned short* __restrict__ in_bfg)
{
    const int b = blockIdx.y, n0 = blockIdx.x * 64;
    __shared__ unsigned short Bsm[64*200];
    __shared__ unsigned short Csm[64*200];
    const int tid = threadIdx.x, lane = tid & 63, wv = tid >> 6;
    const int li = lane & 15, kq = lane >> 4;

    // stage input px-major, fp32 -> bf16; also emit bf16 copy for residual
    {
        const float* src = input + (size_t)b*192*PIX + n0;
        #pragma unroll
        for (int j = 0; j < 6; ++j) {
            int q = tid + 256*j, k = q >> 3, g = (q & 7)*8;
            float4 v0 = *(const float4*)(src + (size_t)k*PIX + g);
            float4 v1 = *(const float4*)(src + (size_t)k*PIX + g + 4);
            unsigned short h0 = f2bf(v0.x), h1 = f2bf(v0.y), h2 = f2bf(v0.z), h3 = f2bf(v0.w);
            unsigned short h4 = f2bf(v1.x), h5 = f2bf(v1.y), h6 = f2bf(v1.z), h7 = f2bf(v1.w);
            Bsm[(g+0)*200 + k] = h0;  Bsm[(g+1)*200 + k] = h1;
            Bsm[(g+2)*200 + k] = h2;  Bsm[(g+3)*200 + k] = h3;
            Bsm[(g+4)*200 + k] = h4;  Bsm[(g+5)*200 + k] = h5;
            Bsm[(g+6)*200 + k] = h6;  Bsm[(g+7)*200 + k] = h7;
            uint4 pk;
            pk.x = h0 | ((unsigned)h1 << 16);  pk.y = h2 | ((unsigned)h3 << 16);
            pk.z = h4 | ((unsigned)h5 << 16);  pk.w = h6 | ((unsigned)h7 << 16);
            *(uint4*)(in_bfg + ((size_t)b*192 + k)*PIX + n0 + g) = pk;
        }
    }
    __syncthreads();

    f32x4 acc[3][4];

    // ---- GEMM A: h = lrelu(W0.in + b0) -> Csm px-major
    #pragma unroll
    for (int m = 0; m < 3; ++m)
        #pragma unroll
        for (int n = 0; n < 4; ++n) acc[m][n] = {0.f,0.f,0.f,0.f};
    for (int kc = 0; kc < 6; ++kc) {
        short8 a[3];
        #pragma unroll
        for (int m = 0; m < 3; ++m)
            a[m] = *(const short8*)(w0f + ((kc*12 + wv*3 + m)*64 + lane)*8);
        #pragma unroll
        for (int n = 0; n < 4; ++n) {
            short8 fb = *(const short8*)(Bsm + (n*16 + li)*200 + kc*32 + kq*8);
            #pragma unroll
            for (int m = 0; m < 3; ++m)
                acc[m][n] = __builtin_amdgcn_mfma_f32_16x16x32_bf16(a[m], fb, acc[m][n], 0,0,0);
        }
    }
    #pragma unroll
    for (int m = 0; m < 3; ++m) {
        int o0 = (wv*3 + m)*16 + kq*4;
        #pragma unroll
        for (int n = 0; n < 4; ++n) {
            int px = n*16 + li;
            ushort4 w;
            unsigned short* wp = (unsigned short*)&w;
            #pragma unroll
            for (int r = 0; r < 4; ++r) {
                float v = acc[m][n][r] + b0[o0 + r];
                v = v > 0.f ? v : 0.1f*v;
                wp[r] = f2bf(v);
            }
            *(ushort4*)(Csm + px*200 + o0) = w;
        }
    }
    __syncthreads();

    // ---- GEMM B: x = W1.h + b1 -> Bsm px-major + global xg
    #pragma unroll
    for (int m = 0; m < 3; ++m)
        #pragma unroll
        for (int n = 0; n < 4; ++n) acc[m][n] = {0.f,0.f,0.f,0.f};
    for (int kc = 0; kc < 6; ++kc) {
        short8 a[3];
        #pragma unroll
        for (int m = 0; m < 3; ++m)
            a[m] = *(const short8*)(w1f + ((kc*12 + wv*3 + m)*64 + lane)*8);
        #pragma unroll
        for (int n = 0; n < 4; ++n) {
            short8 fb = *(const short8*)(Csm + (n*16 + li)*200 + kc*32 + kq*8);
            #pragma unroll
            for (int m = 0; m < 3; ++m)
                acc[m][n] = __builtin_amdgcn_mfma_f32_16x16x32_bf16(a[m], fb, acc[m][n], 0,0,0);
        }
    }
    #pragma unroll
    for (int m = 0; m < 3; ++m) {
        int o0 = (wv*3 + m)*16 + kq*4;
        #pragma unroll
        for (int n = 0; n < 4; ++n) {
            int px = n*16 + li;
            ushort4 w;
            unsigned short* wp = (unsigned short*)&w;
            #pragma unroll
            for (int r = 0; r < 4; ++r) {
                float v = acc[m][n][r] + b1[o0 + r];
                unsigned short h = f2bf(v);
                wp[r] = h;
                xg[((size_t)b*192 + o0 + r)*PIX + n0 + px] = h;
            }
            *(ushort4*)(Bsm + px*200 + o0) = w;
        }
    }
    __syncthreads();

    // ---- GEMM C: y0 = lrelu(Ws0x.x + bs0 + tc[mask]) -> Csm px-major -> y0T
    #pragma unroll
    for (int m = 0; m < 3; ++m)
        #pragma unroll
        for (int n = 0; n < 4; ++n) acc[m][n] = {0.f,0.f,0.f,0.f};
    for (int kc = 0; kc < 6; ++kc) {
        short8 a[3];
        #pragma unroll
        for (int m = 0; m < 3; ++m)
            a[m] = *(const short8*)(ws0xf + ((kc*12 + wv*3 + m)*64 + lane)*8);
        #pragma unroll
        for (int n = 0; n < 4; ++n) {
            short8 fb = *(const short8*)(Bsm + (n*16 + li)*200 + kc*32 + kq*8);
            #pragma unroll
            for (int m = 0; m < 3; ++m)
                acc[m][n] = __builtin_amdgcn_mfma_f32_16x16x32_bf16(a[m], fb, acc[m][n], 0,0,0);
        }
    }
    int mi_[4];
    #pragma unroll
    for (int n = 0; n < 4; ++n) mi_[n] = mask[b*PIX + n0 + n*16 + li];
    #pragma unroll
    for (int m = 0; m < 3; ++m) {
        int o0 = (wv*3 + m)*16 + kq*4;
        #pragma unroll
        for (int n = 0; n < 4; ++n) {
            int px = n*16 + li;
            const float* tcb = tc + (b*16 + mi_[n])*192;
            ushort4 w;
            unsigned short* wp = (unsigned short*)&w;
            #pragma unroll
            for (int r = 0; r < 4; ++r) {
                float v = acc[m][n][r] + bs0[o0 + r] + tcb[o0 + r];
                v = v > 0.f ? v : 0.1f*v;
                wp[r] = f2bf(v);
            }
            *(ushort4*)(Csm + px*200 + o0) = w;
        }
    }
    __syncthreads();
    #pragma unroll
    for (int j = 0; j < 6; ++j) {
        int u = tid + 256*j;
        int px = u / 24, chunk = u % 24;
        uint4 v = *(const uint4*)(Csm + px*200 + chunk*8);
        *(uint4*)(y0t + ((size_t)(b*4096 + n0 + px))*192 + chunk*8) = v;
    }
}

// ---- 3x3 conv: 1 row/block, 4 waves (disjoint m), full-row N per wave ---
// Weights read once per block; dbuf per-kc staging; 2 blocks/CU overlap.
__global__ __launch_bounds__(256) void k_conv3r(
    const unsigned short* __restrict__ wc3f,
    const unsigned short* __restrict__ y0t,   // [b][4096 px][192 c]
    const float* __restrict__ bias,
    unsigned short* __restrict__ y1)          // [b][c][4096 px]
{
    const int b = blockIdx.y, h = blockIdx.x;
    __shared__ unsigned short Bs[2][3*66*40]; // [buf][dr][pxl][40 u16], 80B rows
    const int tid = threadIdx.x, lane = tid & 63, mw = tid >> 6;  // mw = m-quarter
    const int li = lane & 15, kq = lane >> 4;

    // staging: 792 uint4 units (3 rows x 66 pxl x 4 chunks); 4 slots/thread
    size_t src[4]; int dstf[4]; bool ok[4], act[4];
    #pragma unroll
    for (int s = 0; s < 4; ++s) {
        int u = tid + 256*s;
        act[s] = (u < 792);
        int uu = act[s] ? u : 0;
        int row = uu >> 2, chunk = uu & 3;
        int dr = row / 66, pxl = row % 66;
        int hh = h + dr - 1, pxg = pxl - 1;
        ok[s] = act[s] & ((unsigned)hh < 64u) & ((unsigned)pxg < 64u);
        src[s] = ok[s] ? ((size_t)(b*4096 + hh*64 + pxg))*192 + chunk*8 : 0;
        dstf[s] = row*80 + chunk*16;
    }
    const uint4 zz = {0u,0u,0u,0u};
    uint4 v[4];
    #pragma unroll
    for (int s = 0; s < 4; ++s) v[s] = ok[s] ? *(const uint4*)(y0t + src[s]) : zz;
    #pragma unroll
    for (int s = 0; s < 4; ++s) if (act[s]) *(uint4*)((char*)Bs[0] + dstf[s]) = v[s];
    __syncthreads();

    f32x4 acc[3][4];
    #pragma unroll
    for (int m = 0; m < 3; ++m)
        #pragma unroll
        for (int n = 0; n < 4; ++n) acc[m][n] = {0.f,0.f,0.f,0.f};

    for (int kc = 0; kc < 6; ++kc) {
        const int cur = kc & 1;
        if (kc < 5) {   // issue next-chunk loads early (hide under MFMA)
            #pragma unroll
            for (int s = 0; s < 4; ++s)
                v[s] = ok[s] ? *(const uint4*)(y0t + src[s] + (kc+1)*32) : zz;
        }
        const unsigned short* Bc = Bs[cur];
        #pragma unroll
        for (int tap = 0; tap < 9; ++tap) {
            const int dr = tap / 3, dc1 = tap % 3;
            short8 a[3];
            #pragma unroll
            for (int m = 0; m < 3; ++m)
                a[m] = *(const short8*)(wc3f + (((tap*6 + kc)*12 + mw*3 + m)*64 + lane)*8);
            #pragma unroll
            for (int n = 0; n < 4; ++n) {
                int pxi = n*16 + li + dc1;
                short8 fb = *(const short8*)((const char*)Bc + (dr*66 + pxi)*80 + kq*16);
                #pragma unroll
                for (int m = 0; m < 3; ++m)
                    acc[m][n] = __builtin_amdgcn_mfma_f32_16x16x32_bf16(a[m], fb, acc[m][n], 0,0,0);
            }
        }
        if (kc < 5) {   // commit after compute; single barrier per kc
            #pragma unroll
            for (int s = 0; s < 4; ++s)
                if (act[s]) *(uint4*)((char*)Bs[cur^1] + dstf[s]) = v[s];
            __syncthreads();
        }
    }

    #pragma unroll
    for (int m = 0; m < 3; ++m) {
        int oo = (mw*3 + m)*16 + kq*4;
        #pragma unroll
        for (int n = 0; n < 4; ++n) {
            int px = h*64 + n*16 + li;
            #pragma unroll
            for (int r = 0; r < 4; ++r) {
                float vv = acc[m][n][r] + bias[oo + r];
                vv = vv > 0.f ? vv : 0.1f*vv;
                y1[((size_t)b*192 + oo + r)*PIX + px] = f2bf(vv);
            }
        }
    }
}

// ---- fused depthwise-3x3 + dynamic conv + gate-sum; column windows ------
__global__ __launch_bounds__(256) void k_dwdyn3(
    const unsigned short* __restrict__ Y1,
    const unsigned short* __restrict__ X,
    const float* __restrict__ ws2,          // [192][9][9] = [c][j][tap]
    const float* __restrict__ bs2,          // [192*9]
    unsigned short* __restrict__ OP,
    float* __restrict__ gsum)               // [BSZ][192]
{
    const int c = blockIdx.x, b = blockIdx.y;
    __shared__ unsigned short ysm[4096];
    __shared__ unsigned short xsm[4096];
    __shared__ float wsm[81], bsm9[9], red[4];
    const int tid = threadIdx.x;
    const size_t cb = ((size_t)b*192 + c) * PIX;
    #pragma unroll
    for (int j = 0; j < 2; ++j) {
        int i = tid + 256*j;
        *(uint4*)(ysm + i*8) = *(const uint4*)(Y1 + cb + i*8);
        *(uint4*)(xsm + i*8) = *(const uint4*)(X  + cb + i*8);
    }
    if (tid < 81) wsm[tid] = ws2[c*81 + tid];
    else if (tid < 90) bsm9[tid-81] = bs2[c*9 + tid - 81];
    __syncthreads();

    const int w = tid & 63, rg = tid >> 6, h0 = rg * 16;
    const bool wl = (w > 0), wr = (w < 63);

    float ya[3], yb[3], yc[3], xa[3], xb[3], xc[3];
    {
        int h = h0 - 1;
        if (h >= 0) {
            int base = h*64 + w;
            ya[0] = wl ? bf2f(ysm[base-1]) : 0.f;  ya[1] = bf2f(ysm[base]);
            ya[2] = wr ? bf2f(ysm[base+1]) : 0.f;
            xa[0] = wl ? bf2f(xsm[base-1]) : 0.f;  xa[1] = bf2f(xsm[base]);
            xa[2] = wr ? bf2f(xsm[base+1]) : 0.f;
        } else { ya[0]=ya[1]=ya[2]=0.f; xa[0]=xa[1]=xa[2]=0.f; }
        int base = h0*64 + w;
        yb[0] = wl ? bf2f(ysm[base-1]) : 0.f;  yb[1] = bf2f(ysm[base]);
        yb[2] = wr ? bf2f(ysm[base+1]) : 0.f;
        xb[0] = wl ? bf2f(xsm[base-1]) : 0.f;  xb[1] = bf2f(xsm[base]);
        xb[2] = wr ? bf2f(xsm[base+1]) : 0.f;
    }

    float gacc = 0.f;
    #pragma unroll 4
    for (int j = 0; j < 16; ++j) {
        int h = h0 + j;
        if (h + 1 < 64) {
            int base = (h+1)*64 + w;
            yc[0] = wl ? bf2f(ysm[base-1]) : 0.f;  yc[1] = bf2f(ysm[base]);
            yc[2] = wr ? bf2f(ysm[base+1]) : 0.f;
            xc[0] = wl ? bf2f(xsm[base-1]) : 0.f;  xc[1] = bf2f(xsm[base]);
            xc[2] = wr ? bf2f(xsm[base+1]) : 0.f;
        } else { yc[0]=yc[1]=yc[2]=0.f; xc[0]=xc[1]=xc[2]=0.f; }

        float ksp[9];
        #pragma unroll
        for (int t = 0; t < 9; ++t) ksp[t] = bsm9[t];
        #pragma unroll
        for (int tj = 0; tj < 3; ++tj) {
            #pragma unroll
            for (int t = 0; t < 9; ++t) ksp[t] += ya[tj] * wsm[t*9 + tj];
            #pragma unroll
            for (int t = 0; t < 9; ++t) ksp[t] += yb[tj] * wsm[t*9 + 3 + tj];
            #pragma unroll
            for (int t = 0; t < 9; ++t) ksp[t] += yc[tj] * wsm[t*9 + 6 + tj];
        }
        float out = xa[0]*ksp[0] + xa[1]*ksp[1] + xa[2]*ksp[2]
                  + xb[0]*ksp[3] + xb[1]*ksp[4] + xb[2]*ksp[5]
                  + xc[0]*ksp[6] + xc[1]*ksp[7] + xc[2]*ksp[8];
        OP[cb + h*64 + w] = f2bf(out);
        gacc += out;
        #pragma unroll
        for (int t = 0; t < 3; ++t) {
            ya[t] = yb[t]; yb[t] = yc[t];
            xa[t] = xb[t]; xb[t] = xc[t];
        }
    }
    #pragma unroll
    for (int off = 32; off > 0; off >>= 1) gacc += __shfl_down(gacc, off);
    if ((tid & 63) == 0) red[tid >> 6] = gacc;
    __syncthreads();
    if (tid == 0) gsum[b*192 + c] = red[0] + red[1] + red[2] + red[3];
}

// ---- final: gate MLP (per-block) + out = Wo.(g*op) + bo + resid(bf16) ---
__global__ __launch_bounds__(256) void k_gemmo(
    const unsigned short* __restrict__ wof,
    const unsigned short* __restrict__ op,
    const float* __restrict__ bo,
    const float* __restrict__ gsum,
    const float* __restrict__ wc0t, const float* __restrict__ bc0,
    const float* __restrict__ wc1t, const float* __restrict__ bc1,
    const unsigned short* __restrict__ resid,   // bf16 copy of input
    float* __restrict__ out)
{
    const int b = blockIdx.y, n0 = blockIdx.x * 64;
    __shared__ unsigned short Bsm[64*200];
    __shared__ float mean[192], s1[192], gv[192];
    const int tid = threadIdx.x, lane = tid & 63, wv = tid >> 6;
    const int li = lane & 15, kq = lane >> 4;

    if (tid < 192) mean[tid] = gsum[b*192 + tid] * (1.f/4096.f);
    __syncthreads();
    if (tid < 192) {
        float a = bc0[tid];
        for (int i = 0; i < 192; ++i) a += wc0t[i*192 + tid] * mean[i];
        s1[tid] = a > 0.f ? a : 0.1f * a;
    }
    __syncthreads();
    if (tid < 192) {
        float a2 = bc1[tid];
        for (int i = 0; i < 192; ++i) a2 += wc1t[i*192 + tid] * s1[i];
        gv[tid] = 1.f / (1.f + __expf(-a2));
    }
    __syncthreads();

    {
        const unsigned short* src = op + (size_t)b*192*PIX + n0;
        #pragma unroll
        for (int j = 0; j < 6; ++j) {
            int q = tid + 256*j, c = q >> 3, g = (q & 7) * 8;
            uint4 v = *(const uint4*)(src + (size_t)c*PIX + g);
            float gs = gv[c];
            const unsigned short* pv = (const unsigned short*)&v;
            #pragma unroll
            for (int e = 0; e < 8; ++e)
                Bsm[(g+e)*200 + c] = f2bf(bf2f(pv[e]) * gs);
        }
    }
    __syncthreads();

    f32x4 acc[3][4];
    #pragma unroll
    for (int m = 0; m < 3; ++m)
        #pragma unroll
        for (int n = 0; n < 4; ++n) acc[m][n] = {0.f,0.f,0.f,0.f};
    for (int kc = 0; kc < 6; ++kc) {
        short8 a[3];
        #pragma unroll
        for (int m = 0; m < 3; ++m)
            a[m] = *(const short8*)(wof + ((kc*12 + wv*3 + m)*64 + lane)*8);
        #pragma unroll
        for (int n = 0; n < 4; ++n) {
            short8 fb = *(const short8*)(Bsm + (n*16 + li)*200 + kc*32 + kq*8);
            #pragma unroll
            for (int m = 0; m < 3; ++m)
                acc[m][n] = __builtin_amdgcn_mfma_f32_16x16x32_bf16(a[m], fb, acc[m][n], 0,0,0);
        }
    }
    #pragma unroll
    for (int m = 0; m < 3; ++m) {
        int o0 = (wv*3 + m)*16 + kq*4;
        #pragma unroll
        for (int n = 0; n < 4; ++n) {
            int px = n*16 + li;
            #pragma unroll
            for (int r = 0; r < 4; ++r) {
                size_t idx = ((size_t)b*192 + o0 + r)*PIX + n0 + px;
                out[idx] = acc[m][n][r] + bo[o0 + r] + bf2f(resid[idx]);
            }
        }
    }
}

extern "C" void kernel_launch(void* const* d_in, const int* in_sizes, int n_in,
                              void* d_out, int out_size, void* d_ws, size_t ws_size,
                              hipStream_t stream)
{
    const float* input = (const float*)d_in[0];
    const float* lc    = (const float*)d_in[1];
    const int*   mask  = (const int*)d_in[2];
    const float* w0  = (const float*)d_in[3];
    const float* b0  = (const float*)d_in[4];
    const float* w1  = (const float*)d_in[5];
    const float* b1  = (const float*)d_in[6];
    const float* ws0 = (const float*)d_in[7];
    const float* bs0 = (const float*)d_in[8];
    const float* ws1 = (const float*)d_in[9];
    const float* bs1 = (const float*)d_in[10];
    const float* ws2 = (const float*)d_in[11];
    const float* bs2 = (const float*)d_in[12];
    const float* wc0 = (const float*)d_in[13];
    const float* bc0 = (const float*)d_in[14];
    const float* wc1 = (const float*)d_in[15];
    const float* bc1 = (const float*)d_in[16];
    const float* wo  = (const float*)d_in[17];
    const float* bo  = (const float*)d_in[18];

    char* ws = (char*)d_ws;
    size_t off = 0;
    auto alloc = [&](size_t bytes) {
        void* p = ws + off; off = (off + bytes + 255) & ~(size_t)255; return p;
    };
    const size_t act_b = (size_t)BSZ * CH * PIX * 2;
    unsigned short* x_bf  = (unsigned short*)alloc(act_b);
    unsigned short* y0t   = (unsigned short*)alloc(act_b);   // [b][px][c]
    unsigned short* y1_bf = (unsigned short*)alloc(act_b);
    unsigned short* op_bf = (unsigned short*)alloc(act_b);
    unsigned short* in_bf = (unsigned short*)alloc(act_b);   // bf16 resid copy
    unsigned short* w0f   = (unsigned short*)alloc(36864*2);
    unsigned short* w1f   = (unsigned short*)alloc(36864*2);
    unsigned short* ws0xf = (unsigned short*)alloc(36864*2);
    unsigned short* wof   = (unsigned short*)alloc(36864*2);
    unsigned short* wc3f  = (unsigned short*)alloc(331776*2);
    float* tc    = (float*)alloc(8*16*192*4);
    float* gsum  = (float*)alloc(1536*4);
    float* wc0t  = (float*)alloc(36864*4);
    float* wc1t  = (float*)alloc(36864*4);

    k_prep_w<<<2256, 256, 0, stream>>>(w0, w1, ws0, wo, ws1, lc, wc0, wc1,
                                       w0f, w1f, ws0xf, wof, wc3f, tc, wc0t, wc1t);

    dim3 gg(64, 8);
    k_fused3<<<gg, 256, 0, stream>>>(input, w0f, w1f, ws0xf, b0, b1, bs0, tc, mask,
                                     x_bf, y0t, in_bf);
    k_conv3r<<<gg, 256, 0, stream>>>(wc3f, y0t, bs1, y1_bf);
    k_dwdyn3<<<dim3(192, 8), 256, 0, stream>>>(y1_bf, x_bf, ws2, bs2, op_bf, gsum);
    k_gemmo<<<gg, 256, 0, stream>>>(wof, op_bf, bo, gsum, wc0t, bc0, wc1t, bc1,
                                    in_bf, (float*)d_out);
}

// Round 11
// 216.814 us; speedup vs baseline: 1.0659x; 1.0659x over previous
//
#include <hip/hip_runtime.h>
#include <hip/hip_bf16.h>

#define CH   192
#define PIX  4096   // 64*64 per image
#define BSZ  8

using f32x4  = __attribute__((ext_vector_type(4))) float;
using short8 = __attribute__((ext_vector_type(8))) short;

__device__ __forceinline__ float bf2f(unsigned short u) {
    union { unsigned u32; float f; } x; x.u32 = ((unsigned)u) << 16; return x.f;
}
__device__ __forceinline__ unsigned short f2bf(float f) {
    union { float f; unsigned u; } x; x.f = f;
    unsigned u = x.u;
    unsigned r = (u + 0x7FFFu + ((u >> 16) & 1u)) >> 16;  // RNE
    return (unsigned short)r;
}

// ---- prep: weights -> bf16 fragment-ordered; + tc; + gate-w transpose ---
__global__ void k_prep_w(const float* __restrict__ w0, const float* __restrict__ w1,
                         const float* __restrict__ ws0, const float* __restrict__ wo,
                         const float* __restrict__ ws1, const float* __restrict__ lc,
                         const float* __restrict__ wc0, const float* __restrict__ wc1,
                         unsigned short* __restrict__ w0f, unsigned short* __restrict__ w1f,
                         unsigned short* __restrict__ ws0xf, unsigned short* __restrict__ wof,
                         unsigned short* __restrict__ wc3f, float* __restrict__ tc,
                         float* __restrict__ wc0t, float* __restrict__ wc1t) {
    int i = blockIdx.x * 256 + threadIdx.x;
    if (i < 4*36864) {
        int which = i / 36864, j = i % 36864;
        int kc = j / 6144, r = j % 6144, mf = r / 512, r2 = r % 512;
        int l = r2 >> 3, e = r2 & 7;
        int o = mf*16 + (l & 15), k = kc*32 + ((l >> 4) << 3) + e;
        float v;
        unsigned short* dst;
        if (which == 0)      { v = w0[o*192 + k];  dst = w0f;   }
        else if (which == 1) { v = w1[o*192 + k];  dst = w1f;   }
        else if (which == 2) { v = ws0[o*384 + k]; dst = ws0xf; }
        else                 { v = wo[o*192 + k];  dst = wof;   }
        dst[j] = f2bf(v);
        return;
    }
    i -= 4*36864;
    if (i < 331776) {
        int tk = i / 6144, tap = tk / 6, kc = tk % 6;
        int r = i % 6144, mf = r / 512, r2 = r % 512;
        int l = r2 >> 3, e = r2 & 7;
        int o = mf*16 + (l & 15), c = kc*32 + ((l >> 4) << 3) + e;
        wc3f[i] = f2bf(ws1[(o*192 + c)*9 + tap]);
        return;
    }
    i -= 331776;
    if (i < 24576) {
        int bm = i / 192, o = i % 192;
        const float* wr = ws0 + o*384 + 192;
        const float* cb = lc + bm*192;
        float a = 0.f;
        for (int c2 = 0; c2 < 192; ++c2) a += wr[c2] * cb[c2];
        tc[i] = a;
        return;
    }
    i -= 24576;
    if (i < 36864) { int o = i / 192, c = i % 192; wc0t[c*192 + o] = wc0[o*192 + c]; return; }
    i -= 36864;
    if (i < 36864) { int o = i / 192, c = i % 192; wc1t[c*192 + o] = wc1[o*192 + c]; }
}

// ---- fused triple 1x1 GEMM: input(fp32) -> h -> x -> y0T + in_bf --------
__global__ __launch_bounds__(256) void k_fused3(
    const float* __restrict__ input,
    const unsigned short* __restrict__ w0f,
    const unsigned short* __restrict__ w1f,
    const unsigned short* __restrict__ ws0xf,
    const float* __restrict__ b0, const float* __restrict__ b1,
    const float* __restrict__ bs0,
    const float* __restrict__ tc, const int* __restrict__ mask,
    unsigned short* __restrict__ xg, unsigned short* __restrict__ y0t,
    unsigned short* __restrict__ in_bfg)
{
    const int b = blockIdx.y, n0 = blockIdx.x * 64;
    __shared__ unsigned short Bsm[64*200];
    __shared__ unsigned short Csm[64*200];
    const int tid = threadIdx.x, lane = tid & 63, wv = tid >> 6;
    const int li = lane & 15, kq = lane >> 4;

    // stage input px-major, fp32 -> bf16; also emit bf16 copy for residual
    {
        const float* src = input + (size_t)b*192*PIX + n0;
        #pragma unroll
        for (int j = 0; j < 6; ++j) {
            int q = tid + 256*j, k = q >> 3, g = (q & 7)*8;
            float4 v0 = *(const float4*)(src + (size_t)k*PIX + g);
            float4 v1 = *(const float4*)(src + (size_t)k*PIX + g + 4);
            unsigned short h0 = f2bf(v0.x), h1 = f2bf(v0.y), h2 = f2bf(v0.z), h3 = f2bf(v0.w);
            unsigned short h4 = f2bf(v1.x), h5 = f2bf(v1.y), h6 = f2bf(v1.z), h7 = f2bf(v1.w);
            Bsm[(g+0)*200 + k] = h0;  Bsm[(g+1)*200 + k] = h1;
            Bsm[(g+2)*200 + k] = h2;  Bsm[(g+3)*200 + k] = h3;
            Bsm[(g+4)*200 + k] = h4;  Bsm[(g+5)*200 + k] = h5;
            Bsm[(g+6)*200 + k] = h6;  Bsm[(g+7)*200 + k] = h7;
            uint4 pk;
            pk.x = h0 | ((unsigned)h1 << 16);  pk.y = h2 | ((unsigned)h3 << 16);
            pk.z = h4 | ((unsigned)h5 << 16);  pk.w = h6 | ((unsigned)h7 << 16);
            *(uint4*)(in_bfg + ((size_t)b*192 + k)*PIX + n0 + g) = pk;
        }
    }
    __syncthreads();

    f32x4 acc[3][4];

    // ---- GEMM A: h = lrelu(W0.in + b0) -> Csm px-major
    #pragma unroll
    for (int m = 0; m < 3; ++m)
        #pragma unroll
        for (int n = 0; n < 4; ++n) acc[m][n] = {0.f,0.f,0.f,0.f};
    for (int kc = 0; kc < 6; ++kc) {
        short8 a[3];
        #pragma unroll
        for (int m = 0; m < 3; ++m)
            a[m] = *(const short8*)(w0f + ((kc*12 + wv*3 + m)*64 + lane)*8);
        #pragma unroll
        for (int n = 0; n < 4; ++n) {
            short8 fb = *(const short8*)(Bsm + (n*16 + li)*200 + kc*32 + kq*8);
            #pragma unroll
            for (int m = 0; m < 3; ++m)
                acc[m][n] = __builtin_amdgcn_mfma_f32_16x16x32_bf16(a[m], fb, acc[m][n], 0,0,0);
        }
    }
    #pragma unroll
    for (int m = 0; m < 3; ++m) {
        int o0 = (wv*3 + m)*16 + kq*4;
        #pragma unroll
        for (int n = 0; n < 4; ++n) {
            int px = n*16 + li;
            ushort4 w;
            unsigned short* wp = (unsigned short*)&w;
            #pragma unroll
            for (int r = 0; r < 4; ++r) {
                float v = acc[m][n][r] + b0[o0 + r];
                v = v > 0.f ? v : 0.1f*v;
                wp[r] = f2bf(v);
            }
            *(ushort4*)(Csm + px*200 + o0) = w;
        }
    }
    __syncthreads();

    // ---- GEMM B: x = W1.h + b1 -> Bsm px-major + global xg
    #pragma unroll
    for (int m = 0; m < 3; ++m)
        #pragma unroll
        for (int n = 0; n < 4; ++n) acc[m][n] = {0.f,0.f,0.f,0.f};
    for (int kc = 0; kc < 6; ++kc) {
        short8 a[3];
        #pragma unroll
        for (int m = 0; m < 3; ++m)
            a[m] = *(const short8*)(w1f + ((kc*12 + wv*3 + m)*64 + lane)*8);
        #pragma unroll
        for (int n = 0; n < 4; ++n) {
            short8 fb = *(const short8*)(Csm + (n*16 + li)*200 + kc*32 + kq*8);
            #pragma unroll
            for (int m = 0; m < 3; ++m)
                acc[m][n] = __builtin_amdgcn_mfma_f32_16x16x32_bf16(a[m], fb, acc[m][n], 0,0,0);
        }
    }
    #pragma unroll
    for (int m = 0; m < 3; ++m) {
        int o0 = (wv*3 + m)*16 + kq*4;
        #pragma unroll
        for (int n = 0; n < 4; ++n) {
            int px = n*16 + li;
            ushort4 w;
            unsigned short* wp = (unsigned short*)&w;
            #pragma unroll
            for (int r = 0; r < 4; ++r) {
                float v = acc[m][n][r] + b1[o0 + r];
                unsigned short h = f2bf(v);
                wp[r] = h;
                xg[((size_t)b*192 + o0 + r)*PIX + n0 + px] = h;
            }
            *(ushort4*)(Bsm + px*200 + o0) = w;
        }
    }
    __syncthreads();

    // ---- GEMM C: y0 = lrelu(Ws0x.x + bs0 + tc[mask]) -> Csm px-major -> y0T
    #pragma unroll
    for (int m = 0; m < 3; ++m)
        #pragma unroll
        for (int n = 0; n < 4; ++n) acc[m][n] = {0.f,0.f,0.f,0.f};
    for (int kc = 0; kc < 6; ++kc) {
        short8 a[3];
        #pragma unroll
        for (int m = 0; m < 3; ++m)
            a[m] = *(const short8*)(ws0xf + ((kc*12 + wv*3 + m)*64 + lane)*8);
        #pragma unroll
        for (int n = 0; n < 4; ++n) {
            short8 fb = *(const short8*)(Bsm + (n*16 + li)*200 + kc*32 + kq*8);
            #pragma unroll
            for (int m = 0; m < 3; ++m)
                acc[m][n] = __builtin_amdgcn_mfma_f32_16x16x32_bf16(a[m], fb, acc[m][n], 0,0,0);
        }
    }
    int mi_[4];
    #pragma unroll
    for (int n = 0; n < 4; ++n) mi_[n] = mask[b*PIX + n0 + n*16 + li];
    #pragma unroll
    for (int m = 0; m < 3; ++m) {
        int o0 = (wv*3 + m)*16 + kq*4;
        #pragma unroll
        for (int n = 0; n < 4; ++n) {
            int px = n*16 + li;
            const float* tcb = tc + (b*16 + mi_[n])*192;
            ushort4 w;
            unsigned short* wp = (unsigned short*)&w;
            #pragma unroll
            for (int r = 0; r < 4; ++r) {
                float v = acc[m][n][r] + bs0[o0 + r] + tcb[o0 + r];
                v = v > 0.f ? v : 0.1f*v;
                wp[r] = f2bf(v);
            }
            *(ushort4*)(Csm + px*200 + o0) = w;
        }
    }
    __syncthreads();
    #pragma unroll
    for (int j = 0; j < 6; ++j) {
        int u = tid + 256*j;
        int px = u / 24, chunk = u % 24;
        uint4 v = *(const uint4*)(Csm + px*200 + chunk*8);
        *(uint4*)(y0t + ((size_t)(b*4096 + n0 + px))*192 + chunk*8) = v;
    }
}

// ---- 3x3 conv (R7 config): 8 waves (4 M x 2 N); dbuf; issue-early -------
__global__ __launch_bounds__(512) void k_conv3t(
    const unsigned short* __restrict__ wc3f,
    const unsigned short* __restrict__ y0t,   // [b][4096 px][192 c]
    const float* __restrict__ bias,
    unsigned short* __restrict__ y1)          // [b][c][4096 px]
{
    const int b = blockIdx.y, h = blockIdx.x;
    __shared__ unsigned short Bs[2][3*66*40]; // [buf][dr][pxl][40 shorts], 80B rows
    const int tid = threadIdx.x, lane = tid & 63, wv = tid >> 6;
    const int li = lane & 15, kq = lane >> 4;
    const int mw = wv >> 1, nh = wv & 1;      // M-quarter, N-half

    const int u1 = tid + 512;
    const int r0 = tid >> 2,  c0 = tid & 3;
    const int dr0 = r0/66, px0g = r0%66 - 1, hh0 = h + dr0 - 1;
    const bool ok0 = ((unsigned)hh0 < 64u) & ((unsigned)px0g < 64u);
    const size_t s0 = ok0 ? ((size_t)(b*4096 + hh0*64 + px0g))*192 + c0*8 : 0;
    const int o0f = r0*80 + c0*16;
    const int r1 = u1 >> 2,  c1 = u1 & 3;
    const int dr1 = r1/66, px1g = r1%66 - 1, hh1 = h + dr1 - 1;
    const bool act1 = (u1 < 792);
    const bool ok1 = act1 & ((unsigned)hh1 < 64u) & ((unsigned)px1g < 64u);
    const size_t s1 = ok1 ? ((size_t)(b*4096 + hh1*64 + px1g))*192 + c1*8 : 0;
    const int o1f = r1*80 + c1*16;
    const uint4 zz = {0u,0u,0u,0u};

    uint4 v0, v1;
    v0 = ok0 ? *(const uint4*)(y0t + s0) : zz;
    v1 = ok1 ? *(const uint4*)(y0t + s1) : zz;
    *(uint4*)((char*)Bs[0] + o0f) = v0;
    if (act1) *(uint4*)((char*)Bs[0] + o1f) = v1;
    __syncthreads();

    f32x4 acc[3][2];
    #pragma unroll
    for (int m = 0; m < 3; ++m)
        #pragma unroll
        for (int nn = 0; nn < 2; ++nn) acc[m][nn] = {0.f,0.f,0.f,0.f};

    for (int kc = 0; kc < 6; ++kc) {
        const int cur = kc & 1;
        if (kc < 5) {
            v0 = ok0 ? *(const uint4*)(y0t + s0 + (kc+1)*32) : zz;
            v1 = ok1 ? *(const uint4*)(y0t + s1 + (kc+1)*32) : zz;
        }
        const unsigned short* Bc = Bs[cur];
        #pragma unroll
        for (int tap = 0; tap < 9; ++tap) {
            const int dr = tap / 3, dc1 = tap % 3;
            short8 a[3];
            #pragma unroll
            for (int m = 0; m < 3; ++m)
                a[m] = *(const short8*)(wc3f + (((tap*6 + kc)*12 + mw*3 + m)*64 + lane)*8);
            #pragma unroll
            for (int nn = 0; nn < 2; ++nn) {
                int pxi = nh*32 + nn*16 + li + dc1;
                short8 fb = *(const short8*)((const char*)Bc + (dr*66 + pxi)*80 + kq*16);
                #pragma unroll
                for (int m = 0; m < 3; ++m)
                    acc[m][nn] = __builtin_amdgcn_mfma_f32_16x16x32_bf16(a[m], fb, acc[m][nn], 0,0,0);
            }
        }
        if (kc < 5) {
            *(uint4*)((char*)Bs[cur^1] + o0f) = v0;
            if (act1) *(uint4*)((char*)Bs[cur^1] + o1f) = v1;
            __syncthreads();
        }
    }

    #pragma unroll
    for (int m = 0; m < 3; ++m) {
        int oo = (mw*3 + m)*16 + kq*4;
        #pragma unroll
        for (int nn = 0; nn < 2; ++nn) {
            int px = h*64 + nh*32 + nn*16 + li;
            #pragma unroll
            for (int r = 0; r < 4; ++r) {
                float v = acc[m][nn][r] + bias[oo + r];
                v = v > 0.f ? v : 0.1f*v;
                y1[((size_t)b*192 + oo + r)*PIX + px] = f2bf(v);
            }
        }
    }
}

// ---- fused depthwise-3x3 + dynamic conv + gate-sum (R7 reg-weights) -----
__global__ __launch_bounds__(256) void k_dwdyn3(
    const unsigned short* __restrict__ Y1,
    const unsigned short* __restrict__ X,
    const float* __restrict__ ws2,          // [192][9][9] = [c][j][tap]
    const float* __restrict__ bs2,          // [192*9]
    unsigned short* __restrict__ OP,
    float* __restrict__ gsum)               // [BSZ][192]
{
    const int c = blockIdx.x, b = blockIdx.y;
    __shared__ unsigned short ysm[4096];
    __shared__ unsigned short xsm[4096];
    __shared__ float red[4];
    const int tid = threadIdx.x;
    const size_t cb = ((size_t)b*192 + c) * PIX;
    #pragma unroll
    for (int j = 0; j < 2; ++j) {
        int i = tid + 256*j;
        *(uint4*)(ysm + i*8) = *(const uint4*)(Y1 + cb + i*8);
        *(uint4*)(xsm + i*8) = *(const uint4*)(X  + cb + i*8);
    }
    float wreg[81], breg[9];
    #pragma unroll
    for (int t = 0; t < 81; ++t) wreg[t] = ws2[c*81 + t];
    #pragma unroll
    for (int t = 0; t < 9; ++t) breg[t] = bs2[c*9 + t];
    __syncthreads();

    const int w = tid & 63, rg = tid >> 6, h0 = rg * 16;
    const bool wl = (w > 0), wr = (w < 63);

    float ya[3], yb[3], yc[3], xa[3], xb[3], xc[3];
    {
        int h = h0 - 1;
        if (h >= 0) {
            int base = h*64 + w;
            ya[0] = wl ? bf2f(ysm[base-1]) : 0.f;  ya[1] = bf2f(ysm[base]);
            ya[2] = wr ? bf2f(ysm[base+1]) : 0.f;
            xa[0] = wl ? bf2f(xsm[base-1]) : 0.f;  xa[1] = bf2f(xsm[base]);
            xa[2] = wr ? bf2f(xsm[base+1]) : 0.f;
        } else { ya[0]=ya[1]=ya[2]=0.f; xa[0]=xa[1]=xa[2]=0.f; }
        int base = h0*64 + w;
        yb[0] = wl ? bf2f(ysm[base-1]) : 0.f;  yb[1] = bf2f(ysm[base]);
        yb[2] = wr ? bf2f(ysm[base+1]) : 0.f;
        xb[0] = wl ? bf2f(xsm[base-1]) : 0.f;  xb[1] = bf2f(xsm[base]);
        xb[2] = wr ? bf2f(xsm[base+1]) : 0.f;
    }

    float gacc = 0.f;
    #pragma unroll 4
    for (int j = 0; j < 16; ++j) {
        int h = h0 + j;
        if (h + 1 < 64) {
            int base = (h+1)*64 + w;
            yc[0] = wl ? bf2f(ysm[base-1]) : 0.f;  yc[1] = bf2f(ysm[base]);
            yc[2] = wr ? bf2f(ysm[base+1]) : 0.f;
            xc[0] = wl ? bf2f(xsm[base-1]) : 0.f;  xc[1] = bf2f(xsm[base]);
            xc[2] = wr ? bf2f(xsm[base+1]) : 0.f;
        } else { yc[0]=yc[1]=yc[2]=0.f; xc[0]=xc[1]=xc[2]=0.f; }

        float ksp[9];
        #pragma unroll
        for (int t = 0; t < 9; ++t) ksp[t] = breg[t];
        #pragma unroll
        for (int tj = 0; tj < 3; ++tj) {
            #pragma unroll
            for (int t = 0; t < 9; ++t) ksp[t] += ya[tj] * wreg[t*9 + tj];
            #pragma unroll
            for (int t = 0; t < 9; ++t) ksp[t] += yb[tj] * wreg[t*9 + 3 + tj];
            #pragma unroll
            for (int t = 0; t < 9; ++t) ksp[t] += yc[tj] * wreg[t*9 + 6 + tj];
        }
        float out = xa[0]*ksp[0] + xa[1]*ksp[1] + xa[2]*ksp[2]
                  + xb[0]*ksp[3] + xb[1]*ksp[4] + xb[2]*ksp[5]
                  + xc[0]*ksp[6] + xc[1]*ksp[7] + xc[2]*ksp[8];
        OP[cb + h*64 + w] = f2bf(out);
        gacc += out;
        #pragma unroll
        for (int t = 0; t < 3; ++t) {
            ya[t] = yb[t]; yb[t] = yc[t];
            xa[t] = xb[t]; xb[t] = xc[t];
        }
    }
    #pragma unroll
    for (int off = 32; off > 0; off >>= 1) gacc += __shfl_down(gacc, off);
    if ((tid & 63) == 0) red[tid >> 6] = gacc;
    __syncthreads();
    if (tid == 0) gsum[b*192 + c] = red[0] + red[1] + red[2] + red[3];
}

// ---- final: gate MLP (per-block) + out = Wo.(g*op) + bo + resid(bf16) ---
__global__ __launch_bounds__(256) void k_gemmo(
    const unsigned short* __restrict__ wof,
    const unsigned short* __restrict__ op,
    const float* __restrict__ bo,
    const float* __restrict__ gsum,
    const float* __restrict__ wc0t, const float* __restrict__ bc0,
    const float* __restrict__ wc1t, const float* __restrict__ bc1,
    const unsigned short* __restrict__ resid,   // bf16 copy of input
    float* __restrict__ out)
{
    const int b = blockIdx.y, n0 = blockIdx.x * 64;
    __shared__ unsigned short Bsm[64*200];
    __shared__ float mean[192], s1[192], gv[192];
    const int tid = threadIdx.x, lane = tid & 63, wv = tid >> 6;
    const int li = lane & 15, kq = lane >> 4;

    if (tid < 192) mean[tid] = gsum[b*192 + tid] * (1.f/4096.f);
    __syncthreads();
    if (tid < 192) {
        float a = bc0[tid];
        for (int i = 0; i < 192; ++i) a += wc0t[i*192 + tid] * mean[i];
        s1[tid] = a > 0.f ? a : 0.1f * a;
    }
    __syncthreads();
    if (tid < 192) {
        float a2 = bc1[tid];
        for (int i = 0; i < 192; ++i) a2 += wc1t[i*192 + tid] * s1[i];
        gv[tid] = 1.f / (1.f + __expf(-a2));
    }
    __syncthreads();

    {
        const unsigned short* src = op + (size_t)b*192*PIX + n0;
        #pragma unroll
        for (int j = 0; j < 6; ++j) {
            int q = tid + 256*j, c = q >> 3, g = (q & 7) * 8;
            uint4 v = *(const uint4*)(src + (size_t)c*PIX + g);
            float gs = gv[c];
            const unsigned short* pv = (const unsigned short*)&v;
            #pragma unroll
            for (int e = 0; e < 8; ++e)
                Bsm[(g+e)*200 + c] = f2bf(bf2f(pv[e]) * gs);
        }
    }
    __syncthreads();

    f32x4 acc[3][4];
    #pragma unroll
    for (int m = 0; m < 3; ++m)
        #pragma unroll
        for (int n = 0; n < 4; ++n) acc[m][n] = {0.f,0.f,0.f,0.f};
    for (int kc = 0; kc < 6; ++kc) {
        short8 a[3];
        #pragma unroll
        for (int m = 0; m < 3; ++m)
            a[m] = *(const short8*)(wof + ((kc*12 + wv*3 + m)*64 + lane)*8);
        #pragma unroll
        for (int n = 0; n < 4; ++n) {
            short8 fb = *(const short8*)(Bsm + (n*16 + li)*200 + kc*32 + kq*8);
            #pragma unroll
            for (int m = 0; m < 3; ++m)
                acc[m][n] = __builtin_amdgcn_mfma_f32_16x16x32_bf16(a[m], fb, acc[m][n], 0,0,0);
        }
    }
    #pragma unroll
    for (int m = 0; m < 3; ++m) {
        int o0 = (wv*3 + m)*16 + kq*4;
        #pragma unroll
        for (int n = 0; n < 4; ++n) {
            int px = n*16 + li;
            #pragma unroll
            for (int r = 0; r < 4; ++r) {
                size_t idx = ((size_t)b*192 + o0 + r)*PIX + n0 + px;
                out[idx] = acc[m][n][r] + bo[o0 + r] + bf2f(resid[idx]);
            }
        }
    }
}

extern "C" void kernel_launch(void* const* d_in, const int* in_sizes, int n_in,
                              void* d_out, int out_size, void* d_ws, size_t ws_size,
                              hipStream_t stream)
{
    const float* input = (const float*)d_in[0];
    const float* lc    = (const float*)d_in[1];
    const int*   mask  = (const int*)d_in[2];
    const float* w0  = (const float*)d_in[3];
    const float* b0  = (const float*)d_in[4];
    const float* w1  = (const float*)d_in[5];
    const float* b1  = (const float*)d_in[6];
    const float* ws0 = (const float*)d_in[7];
    const float* bs0 = (const float*)d_in[8];
    const float* ws1 = (const float*)d_in[9];
    const float* bs1 = (const float*)d_in[10];
    const float* ws2 = (const float*)d_in[11];
    const float* bs2 = (const float*)d_in[12];
    const float* wc0 = (const float*)d_in[13];
    const float* bc0 = (const float*)d_in[14];
    const float* wc1 = (const float*)d_in[15];
    const float* bc1 = (const float*)d_in[16];
    const float* wo  = (const float*)d_in[17];
    const float* bo  = (const float*)d_in[18];

    char* ws = (char*)d_ws;
    size_t off = 0;
    auto alloc = [&](size_t bytes) {
        void* p = ws + off; off = (off + bytes + 255) & ~(size_t)255; return p;
    };
    const size_t act_b = (size_t)BSZ * CH * PIX * 2;
    unsigned short* x_bf  = (unsigned short*)alloc(act_b);
    unsigned short* y0t   = (unsigned short*)alloc(act_b);   // [b][px][c]
    unsigned short* y1_bf = (unsigned short*)alloc(act_b);
    unsigned short* op_bf = (unsigned short*)alloc(act_b);
    unsigned short* in_bf = (unsigned short*)alloc(act_b);   // bf16 resid copy
    unsigned short* w0f   = (unsigned short*)alloc(36864*2);
    unsigned short* w1f   = (unsigned short*)alloc(36864*2);
    unsigned short* ws0xf = (unsigned short*)alloc(36864*2);
    unsigned short* wof   = (unsigned short*)alloc(36864*2);
    unsigned short* wc3f  = (unsigned short*)alloc(331776*2);
    float* tc    = (float*)alloc(8*16*192*4);
    float* gsum  = (float*)alloc(1536*4);
    float* wc0t  = (float*)alloc(36864*4);
    float* wc1t  = (float*)alloc(36864*4);

    k_prep_w<<<2256, 256, 0, stream>>>(w0, w1, ws0, wo, ws1, lc, wc0, wc1,
                                       w0f, w1f, ws0xf, wof, wc3f, tc, wc0t, wc1t);

    dim3 gg(64, 8);
    k_fused3<<<gg, 256, 0, stream>>>(input, w0f, w1f, ws0xf, b0, b1, bs0, tc, mask,
                                     x_bf, y0t, in_bf);
    k_conv3t<<<gg, 512, 0, stream>>>(wc3f, y0t, bs1, y1_bf);
    k_dwdyn3<<<dim3(192, 8), 256, 0, stream>>>(y1_bf, x_bf, ws2, bs2, op_bf, gsum);
    k_gemmo<<<gg, 256, 0, stream>>>(wof, op_bf, bo, gsum, wc0t, bc0, wc1t, bc1,
                                    in_bf, (float*)d_out);
}